// Round 8
// baseline (149.404 us; speedup 1.0000x reference)
//
#include <hip/hip_runtime.h>

// AdaptiveGN_Patches_Hadamart: per-patch GroupNorm + silu-gate, fp32.
// R7: full register residency. 1024 thr/block, each thread holds 4 float4
// of x AND 4 float4 of y across the reduction barrier, asm-pinned per
// scalar (R4 idiom) so the compiler cannot demote them to post-barrier
// re-loads (as it did in R0). No LDS tile (128 B reduction scratch only).
// Phase 2 is pure FMA + nontemporal store: no loads after the barrier.
// launch_bounds(1024,8) caps VGPR at 64 -> 2 blocks/CU = 32 waves = 100%.

constexpr int CHANNELS = 128;
constexpr int HW = 256;
constexpr int NP = 4;
constexpr int G = 32;
constexpr int CPG = CHANNELS / G;          // 4 channels per group
constexpr float EPS = 1e-5f;

typedef float f32x4 __attribute__((ext_vector_type(4)));

__device__ __forceinline__ float fast_gate(float v) {
    // 1 + silu(v) = 1 + v / (1 + exp(-v)); exp(-v) = exp2(-v*log2(e))
    const float e = __builtin_amdgcn_exp2f(v * -1.44269504088896f);
    return 1.0f + v * __builtin_amdgcn_rcpf(1.0f + e);
}

__global__ __launch_bounds__(1024, 8)
void gn_patch_gate_kernel(const float* __restrict__ x,
                          const float* __restrict__ y,
                          const float* __restrict__ wgt,
                          const float* __restrict__ bvec,
                          float* __restrict__ out)
{
    __shared__ float red[32];

    const int bid = blockIdx.x;
    const int g  = bid & 31;          // group
    const int pj = (bid >> 5) & 3;    // patch col
    const int pi = (bid >> 7) & 3;    // patch row
    const int b  = bid >> 9;          // batch
    const int tid = threadIdx.x;

    const unsigned base =
        (((unsigned)b * CHANNELS + (unsigned)g * CPG) * HW + (unsigned)pi * 64) * HW
        + (unsigned)pj * 64;
    // 1024 threads cover one 64x64 plane in float4s: row=tid>>4, col4=tid&15.
    const unsigned a0 = base + (((unsigned)tid >> 4) << 8) + (((unsigned)tid & 15) << 2);

    // Phase 1: load x+y into registers (one channel plane per k), pin, sum.
    float xr[16], yr[16];
    float s = 0.f, ss = 0.f;
#pragma unroll
    for (int k = 0; k < 4; ++k) {
        const unsigned a = a0 + (unsigned)(k << 16);        // k * 65536
        const float4 v = *reinterpret_cast<const float4*>(x + a);
        const float4 w = *reinterpret_cast<const float4*>(y + a);
        float v0 = v.x, v1 = v.y, v2 = v.z, v3 = v.w;
        float w0 = w.x, w1 = w.y, w2 = w.z, w3 = w.w;
        asm volatile("" : "+v"(v0), "+v"(v1), "+v"(v2), "+v"(v3),
                          "+v"(w0), "+v"(w1), "+v"(w2), "+v"(w3));
        xr[4*k+0] = v0; xr[4*k+1] = v1; xr[4*k+2] = v2; xr[4*k+3] = v3;
        yr[4*k+0] = w0; yr[4*k+1] = w1; yr[4*k+2] = w2; yr[4*k+3] = w3;
        s  += (v0 + v1) + (v2 + v3);
        ss += (v0 * v0 + v1 * v1) + (v2 * v2 + v3 * v3);
    }

    // Wave (64-lane) butterfly reduce, then cross-wave via LDS.
#pragma unroll
    for (int off = 32; off; off >>= 1) {
        s  += __shfl_xor(s, off);
        ss += __shfl_xor(ss, off);
    }
    const int wv = tid >> 6;          // 16 waves
    if ((tid & 63) == 0) { red[wv] = s; red[16 + wv] = ss; }
    __syncthreads();
    float ts = 0.f, tss = 0.f;
#pragma unroll
    for (int q = 0; q < 16; ++q) { ts += red[q]; tss += red[16 + q]; }

    const float inv_n = 1.0f / 16384.0f;
    const float mean = ts * inv_n;
    const float var  = fmaxf(tss * inv_n - mean * mean, 0.f);
    const float rstd = rsqrtf(var + EPS);

    // Per-channel affine folded into scale/shift (channel index == k).
    float scl[CPG], sft[CPG];
#pragma unroll
    for (int cc = 0; cc < CPG; ++cc) {
        const float wc = wgt[g * CPG + cc];
        scl[cc] = wc * rstd;
        sft[cc] = bvec[g * CPG + cc] - mean * rstd * wc;
    }

    // Phase 2: pure compute + NT store — no loads after the barrier.
#pragma unroll
    for (int k = 0; k < 4; ++k) {
        const unsigned a = a0 + (unsigned)(k << 16);
        f32x4 o;
        o.x = (xr[4*k+0] * scl[k] + sft[k]) * fast_gate(yr[4*k+0]);
        o.y = (xr[4*k+1] * scl[k] + sft[k]) * fast_gate(yr[4*k+1]);
        o.z = (xr[4*k+2] * scl[k] + sft[k]) * fast_gate(yr[4*k+2]);
        o.w = (xr[4*k+3] * scl[k] + sft[k]) * fast_gate(yr[4*k+3]);
        __builtin_nontemporal_store(o, reinterpret_cast<f32x4*>(out + a));
    }
}

extern "C" void kernel_launch(void* const* d_in, const int* in_sizes, int n_in,
                              void* d_out, int out_size, void* d_ws, size_t ws_size,
                              hipStream_t stream) {
    const float* x    = (const float*)d_in[0];
    const float* y    = (const float*)d_in[1];
    const float* wgt  = (const float*)d_in[2];
    const float* bvec = (const float*)d_in[3];
    float* out = (float*)d_out;

    const int B = in_sizes[0] / (CHANNELS * HW * HW);   // 8
    const int nblocks = B * NP * NP * G;                // 4096
    gn_patch_gate_kernel<<<dim3(nblocks), dim3(1024), 0, stream>>>(x, y, wgt, bvec, out);
}